// Round 1
// baseline (63.208 us; speedup 1.0000x reference)
//
#include <hip/hip_runtime.h>

// FlatColorShader: out[b,h,w,:] = mean over 3 verts of verts_colors[faces[f]]
// where f = pix_to_face[b,h,w,0], or 0 if f < 0.
//
// Stage 1: avg[f][3] = (verts[i0] + verts[i1] + verts[i2]) / 3   (F=200K, -> d_ws)
// Stage 2: per pixel gather from avg table (2.4 MB, L2-resident), 4 pixels/thread
//          so id loads are int4 (16B) and output stores are 3x float4 (48B aligned).
//
// Integer inputs (faces, pix_to_face) are int32 on device (JAX x64 disabled
// downcasts jnp.int64 -> int32; harness passes integers as int*).

__global__ void face_avg_kernel(const float* __restrict__ verts,
                                const int*   __restrict__ faces,
                                float*       __restrict__ avg,
                                int F) {
    int f = blockIdx.x * blockDim.x + threadIdx.x;
    if (f >= F) return;
    int i0 = faces[3 * f + 0];
    int i1 = faces[3 * f + 1];
    int i2 = faces[3 * f + 2];
    const float s = 1.0f / 3.0f;
    float r = (verts[3 * i0 + 0] + verts[3 * i1 + 0] + verts[3 * i2 + 0]) * s;
    float g = (verts[3 * i0 + 1] + verts[3 * i1 + 1] + verts[3 * i2 + 1]) * s;
    float b = (verts[3 * i0 + 2] + verts[3 * i1 + 2] + verts[3 * i2 + 2]) * s;
    avg[3 * f + 0] = r;
    avg[3 * f + 1] = g;
    avg[3 * f + 2] = b;
}

__global__ void shade_kernel(const int*   __restrict__ pix,
                             const float* __restrict__ avg,
                             float*       __restrict__ out,
                             int n_pix) {
    int t = blockIdx.x * blockDim.x + threadIdx.x;
    int p0 = t * 4;
    if (p0 >= n_pix) return;

    if (p0 + 3 < n_pix) {
        // fast path: full group of 4 pixels
        int4 ids = reinterpret_cast<const int4*>(pix)[t];
        int idv[4] = {ids.x, ids.y, ids.z, ids.w};
        float c[12];
#pragma unroll
        for (int j = 0; j < 4; ++j) {
            int f = idv[j];
            float r = 0.0f, g = 0.0f, b = 0.0f;
            if (f >= 0) {
                r = avg[3 * f + 0];
                g = avg[3 * f + 1];
                b = avg[3 * f + 2];
            }
            c[3 * j + 0] = r;
            c[3 * j + 1] = g;
            c[3 * j + 2] = b;
        }
        // group byte offset = t * 48, 16B aligned
        float4* o = reinterpret_cast<float4*>(out) + t * 3;
        o[0] = make_float4(c[0], c[1], c[2], c[3]);
        o[1] = make_float4(c[4], c[5], c[6], c[7]);
        o[2] = make_float4(c[8], c[9], c[10], c[11]);
    } else {
        // tail (not hit for 8M pixels, kept for generality)
        for (int p = p0; p < n_pix; ++p) {
            int f = pix[p];
            float r = 0.0f, g = 0.0f, b = 0.0f;
            if (f >= 0) {
                r = avg[3 * f + 0];
                g = avg[3 * f + 1];
                b = avg[3 * f + 2];
            }
            out[3 * p + 0] = r;
            out[3 * p + 1] = g;
            out[3 * p + 2] = b;
        }
    }
}

extern "C" void kernel_launch(void* const* d_in, const int* in_sizes, int n_in,
                              void* d_out, int out_size, void* d_ws, size_t ws_size,
                              hipStream_t stream) {
    const float* verts = (const float*)d_in[0];   // [V,3] f32
    const int*   faces = (const int*)d_in[1];     // [F,3] i32
    const int*   pix   = (const int*)d_in[2];     // [B,H,W,1] i32
    float*       out   = (float*)d_out;           // [B,H,W,3] f32
    float*       avg   = (float*)d_ws;            // [F,3] f32 scratch (2.4 MB)

    int F     = in_sizes[1] / 3;
    int n_pix = in_sizes[2];

    {
        int threads = 256;
        int blocks  = (F + threads - 1) / threads;
        face_avg_kernel<<<blocks, threads, 0, stream>>>(verts, faces, avg, F);
    }
    {
        int n_groups = (n_pix + 3) / 4;
        int threads  = 256;
        int blocks   = (n_groups + threads - 1) / threads;
        shade_kernel<<<blocks, threads, 0, stream>>>(pix, avg, out, n_pix);
    }
}